// Round 5
// baseline (616.373 us; speedup 1.0000x reference)
//
#include <hip/hip_runtime.h>
#include <hip/hip_bf16.h>
#include <math.h>

using bf16x8 = __attribute__((ext_vector_type(8))) __bf16;
using f32x4  = __attribute__((ext_vector_type(4))) float;
typedef unsigned short ushort_t;

#define BS    8192
#define CDIM  512
#define MROWS 32768
#define NC    8                 // n-chunks (grid.x)
#define CHUNK (MROWS / NC)      // 4096
#define TN    32                // B-tile rows per iteration
#define TQ    256               // queries per block (64 per wave)
#define KTOP  5
#define ITERS (CHUNK / TN)      // 128
#define KEY_INIT 0x3FFF8000u    // enc_key(-2.0f, 0)

// ---------- key packing: monotonic fp32 order bits [31:15] | index [14:0] ----
__device__ __forceinline__ unsigned enc_key(float s, int n) {
    unsigned u = __float_as_uint(s);
    u ^= (unsigned)((int)u >> 31) | 0x80000000u;   // monotonic map
    return (u & 0xFFFF8000u) | (unsigned)n;
}
__device__ __forceinline__ float dec_score(unsigned k) {
    unsigned u = k & 0xFFFF8000u;
    u = (u & 0x80000000u) ? (u ^ 0x80000000u) : ~u;
    return __uint_as_float(u);
}

// sorted-descending top-5 list of packed keys, branchless bubble insert
__device__ __forceinline__ void ins_nb(unsigned (&ks)[KTOP], unsigned k) {
    unsigned t = k;
#pragma unroll
    for (int j = 0; j < KTOP; ++j) {
        unsigned hi = t > ks[j] ? t : ks[j];
        unsigned lo = t > ks[j] ? ks[j] : t;
        ks[j] = hi; t = lo;
    }
}

// max across a 16-lane DPP row (VALU only — keeps syncs off the LDS pipe)
__device__ __forceinline__ float dpp_fmax16(float x) {
    int t;
    t = __builtin_amdgcn_update_dpp(0, __float_as_int(x), 0xB1, 0xF, 0xF, true);  // xor 1 (quad_perm)
    x = fmaxf(x, __int_as_float(t));
    t = __builtin_amdgcn_update_dpp(0, __float_as_int(x), 0x4E, 0xF, 0xF, true);  // xor 2 (quad_perm)
    x = fmaxf(x, __int_as_float(t));
    t = __builtin_amdgcn_update_dpp(0, __float_as_int(x), 0x141, 0xF, 0xF, true); // xor 4 (row_half_mirror)
    x = fmaxf(x, __int_as_float(t));
    t = __builtin_amdgcn_update_dpp(0, __float_as_int(x), 0x140, 0xF, 0xF, true); // xor 8 (row_mirror)
    x = fmaxf(x, __int_as_float(t));
    return x;
}

// ---------- kernel 1: row L2-normalize fp32 -> bf16 (both inputs, one grid) --
__global__ void nrm_cast2(const float* __restrict__ memM, ushort_t* __restrict__ mn,
                          const float* __restrict__ x, ushort_t* __restrict__ qn) {
    int wave = threadIdx.x >> 6, lane = threadIdx.x & 63;
    int row = blockIdx.x * 4 + wave;
    const float* in;
    ushort_t* out;
    if (row < MROWS) { in = memM + (size_t)row * CDIM; out = mn + (size_t)row * CDIM; }
    else             { int r = row - MROWS; in = x + (size_t)r * CDIM; out = qn + (size_t)r * CDIM; }
    const float* rp = in + lane * 8;
    float4 v0 = *(const float4*)rp;
    float4 v1 = *(const float4*)(rp + 4);
    float ss = v0.x * v0.x + v0.y * v0.y + v0.z * v0.z + v0.w * v0.w
             + v1.x * v1.x + v1.y * v1.y + v1.z * v1.z + v1.w * v1.w;
#pragma unroll
    for (int d = 1; d < 64; d <<= 1) ss += __shfl_xor(ss, d);
    float sc = 1.0f / fmaxf(sqrtf(ss), 1e-12f);
    bf16x8 o;
    o[0] = (__bf16)(v0.x * sc); o[1] = (__bf16)(v0.y * sc);
    o[2] = (__bf16)(v0.z * sc); o[3] = (__bf16)(v0.w * sc);
    o[4] = (__bf16)(v1.x * sc); o[5] = (__bf16)(v1.y * sc);
    o[6] = (__bf16)(v1.z * sc); o[7] = (__bf16)(v1.w * sc);
    *(bf16x8*)(out + lane * 8) = o;
}

// ---------- async staging with XOR chunk swizzle (unchanged from R4) --------
__device__ __forceinline__ void stage_tile(const ushort_t* __restrict__ mn, int nb,
                                           uint4* buf, int wave, int lane) {
    const int r0 = wave * 8;
#pragma unroll
    for (int j = 0; j < 8; ++j) {
        const int row = r0 + j;
        const ushort_t* src = mn + (size_t)(nb + row) * CDIM + ((lane ^ (row & 7)) * 8);
        __builtin_amdgcn_global_load_lds(
            (const __attribute__((address_space(1))) void*)src,
            (__attribute__((address_space(3))) void*)(buf + row * 64),
            16, 0, 0);
    }
}

// ---------- kernel 2: fused bf16 MFMA sim + per-chunk top-5 -----------------
// grid = (NC, BS/TQ) = (8,32) = 256 blocks = 1/CU. Block = 4 waves, 1/SIMD.
// Each wave holds 64 queries' A-fragments resident (256 regs; AGPR-backed at
// 1 wave/EU) -> each B-frag LDS read feeds 8 MFMAs: LDS traffic/CU halves vs
// Q=32 and MFMA becomes the binding pipe.
__global__ __launch_bounds__(256, 1) void simtopk(
        const ushort_t* __restrict__ qn, const ushort_t* __restrict__ mn,
        unsigned* __restrict__ cand) {
    __shared__ uint4 Bt[2][TN * 64];          // 2 x 32 KiB = 65536 B exactly

    const int tid  = threadIdx.x;
    const int wave = tid >> 6, lane = tid & 63;
    const int quad = lane >> 4, c16 = lane & 15;
    const int nc = blockIdx.x;                 // same-nc blocks share an XCD's L2 chunk
    const int qt = blockIdx.y;
    const int qw = qt * TQ + wave * 64;        // wave's 64 query rows
    const int nb0 = nc * CHUNK;

    // persistent A fragments: 4 q-subtiles x 16 K-chunks = 256 regs
    bf16x8 a[4][16];
#pragma unroll
    for (int s = 0; s < 4; ++s) {
        const ushort_t* p = qn + (size_t)(qw + s * 16 + c16) * CDIM + quad * 8;
#pragma unroll
        for (int kc = 0; kc < 16; ++kc)
            a[s][kc] = *(const bf16x8*)(p + kc * 32);
    }

    unsigned keys[16][KTOP];
    float thr[16];
#pragma unroll
    for (int l = 0; l < 16; ++l) {
        thr[l] = -2.0f;
#pragma unroll
        for (int j = 0; j < KTOP; ++j) keys[l][j] = KEY_INIT;
    }

    const int sw = c16 & 7;                    // read-side slot XOR

    stage_tile(mn, nb0, &Bt[0][0], wave, lane);   // prefetch tile 0

    for (int it = 0; it < ITERS; ++it) {
        __syncthreads();   // drains async loads issued a full iter ago; syncs waves
        if (it + 1 < ITERS)
            stage_tile(mn, nb0 + (it + 1) * TN, &Bt[(it + 1) & 1][0], wave, lane);

        const uint4* bb = &Bt[it & 1][c16 * 64];
        f32x4 acc[4][2];
#pragma unroll
        for (int s = 0; s < 4; ++s) {
            acc[s][0] = (f32x4){0.f, 0.f, 0.f, 0.f};
            acc[s][1] = (f32x4){0.f, 0.f, 0.f, 0.f};
        }
#pragma unroll
        for (int kc = 0; kc < 16; ++kc) {
            const int slot = (kc * 4 + quad) ^ sw;
            bf16x8 b0 = *(const bf16x8*)(bb + slot);              // row c16
            bf16x8 b1 = *(const bf16x8*)(bb + 16 * 64 + slot);    // row 16+c16
#pragma unroll
            for (int s = 0; s < 4; ++s) {
                acc[s][0] = __builtin_amdgcn_mfma_f32_16x16x32_bf16(a[s][kc], b0, acc[s][0], 0, 0, 0);
                acc[s][1] = __builtin_amdgcn_mfma_f32_16x16x32_bf16(a[s][kc], b1, acc[s][1], 0, 0, 0);
            }
        }

        const int nb = nb0 + it * TN;
        const int n0 = nb + c16, n1 = nb + 16 + c16;
        // shared-threshold filter: thr[l] <= true running 5th-best of q-row l
#pragma unroll
        for (int s = 0; s < 4; ++s) {
#pragma unroll
            for (int j = 0; j < 4; ++j) {
                const int l = s * 4 + j;
                if (acc[s][0][j] > thr[l]) ins_nb(keys[l], enc_key(acc[s][0][j], n0));
                if (acc[s][1][j] > thr[l]) ins_nb(keys[l], enc_key(acc[s][1][j], n1));
            }
        }
        if ((it & 3) == 3) {
#pragma unroll
            for (int l = 0; l < 16; ++l)
                thr[l] = dpp_fmax16(fmaxf(thr[l], dec_score(keys[l][KTOP - 1])));
        }
    }

    // merge the 16 column-lanes of each quad (disjoint n subsets -> union top5)
#pragma unroll
    for (int d = 1; d <= 8; d <<= 1) {
#pragma unroll
        for (int l = 0; l < 16; ++l) {
            unsigned rk[KTOP];
#pragma unroll
            for (int j = 0; j < KTOP; ++j) rk[j] = (unsigned)__shfl_xor((int)keys[l][j], d);
#pragma unroll
            for (int j = 0; j < KTOP; ++j) ins_nb(keys[l], rk[j]);
        }
    }

    // writer: lane c16==l emits list l for q-row qw + (l>>2)*16 + quad*4 + (l&3)
#pragma unroll
    for (int l = 0; l < 16; ++l) {
        if (c16 == l) {
            const int q = qw + (l >> 2) * 16 + quad * 4 + (l & 3);
            unsigned* cp = cand + ((size_t)q * NC + nc) * KTOP;
#pragma unroll
            for (int j = 0; j < KTOP; ++j) cp[j] = keys[l][j];
        }
    }
}

// ---------- kernel 3: global top-5 merge + softmax + gather + residual ------
__global__ void epilogue(const float* __restrict__ x, const float* __restrict__ mem,
                         const unsigned* __restrict__ cand, float* __restrict__ out) {
    int wave = threadIdx.x >> 6, lane = threadIdx.x & 63;
    int q = blockIdx.x * 4 + wave;

    unsigned key = (lane < NC * KTOP) ? cand[(size_t)q * (NC * KTOP) + lane] : 0u;
    float s[KTOP]; int id[KTOP];
#pragma unroll
    for (int k = 0; k < KTOP; ++k) {
        unsigned m = key;
#pragma unroll
        for (int d = 32; d; d >>= 1) {
            unsigned o = (unsigned)__shfl_xor((int)m, d);
            m = o > m ? o : m;
        }
        s[k] = dec_score(m);
        id[k] = (int)(m & 0x7FFFu);
        unsigned long long b = __ballot(key == m);
        int first = __ffsll((long long)b) - 1;
        if (lane == first) key = 0u;
    }
    float w[KTOP], sum = 0.f;
#pragma unroll
    for (int k = 0; k < KTOP; ++k) { w[k] = expf(s[k] - s[0]); sum += w[k]; }
    float inv = 0.5f / sum;

    int c = lane * 8;
    const float4* xp = (const float4*)(x + (size_t)q * CDIM + c);
    float4 o0 = xp[0], o1 = xp[1];
#pragma unroll
    for (int k = 0; k < KTOP; ++k) {
        float wk = w[k] * inv;
        const float4* mp = (const float4*)(mem + (size_t)id[k] * CDIM + c);
        float4 g0 = mp[0], g1 = mp[1];
        o0.x += wk * g0.x; o0.y += wk * g0.y; o0.z += wk * g0.z; o0.w += wk * g0.w;
        o1.x += wk * g1.x; o1.y += wk * g1.y; o1.z += wk * g1.z; o1.w += wk * g1.w;
    }
    float* op = out + (size_t)q * CDIM + c;
    *(float4*)op = o0;
    *(float4*)(op + 4) = o1;
}

// ---------- launcher --------------------------------------------------------
extern "C" void kernel_launch(void* const* d_in, const int* in_sizes, int n_in,
                              void* d_out, int out_size, void* d_ws, size_t ws_size,
                              hipStream_t stream) {
    const float* x    = (const float*)d_in[0];   // [4,2048,512] fp32
    const float* memM = (const float*)d_in[1];   // [32768,512] fp32
    float* out = (float*)d_out;                  // fp32 output

    // workspace layout: mn bf16 [M][C] | qn bf16 [BS][C] | cand u32 [BS][NC][5]
    ushort_t* mn = (ushort_t*)d_ws;
    ushort_t* qn = mn + (size_t)MROWS * CDIM;
    unsigned* cand = (unsigned*)(qn + (size_t)BS * CDIM);

    nrm_cast2<<<(MROWS + BS) / 4, 256, 0, stream>>>(memM, mn, x, qn);
    simtopk<<<dim3(NC, BS / TQ), 256, 0, stream>>>(qn, mn, cand);
    epilogue<<<BS / 4, 256, 0, stream>>>(x, memM, cand, out);
}

// Round 6
// 371.570 us; speedup vs baseline: 1.6588x; 1.6588x over previous
//
#include <hip/hip_runtime.h>
#include <hip/hip_bf16.h>
#include <math.h>

using f32x4 = __attribute__((ext_vector_type(4))) float;
typedef unsigned char u8;

#define BS    8192
#define CDIM  512
#define MROWS 32768
#define NC    8                 // n-chunks (grid.x)
#define CHUNK (MROWS / NC)      // 4096
#define TN    32                // B-tile rows per iteration
#define TQ    128               // queries per block (32 per wave)
#define KTOP  5
#define ITERS (CHUNK / TN)      // 128
#define ROWB  512               // fp8 row bytes
#define KEY_INIT 0x3FFF8000u    // enc_key(-2.0f, 0)

// ---------- key packing: monotonic fp32 order bits [31:15] | index [14:0] ----
__device__ __forceinline__ unsigned enc_key(float s, int n) {
    unsigned u = __float_as_uint(s);
    u ^= (unsigned)((int)u >> 31) | 0x80000000u;   // monotonic map
    return (u & 0xFFFF8000u) | (unsigned)n;
}
__device__ __forceinline__ float dec_score(unsigned k) {
    unsigned u = k & 0xFFFF8000u;
    u = (u & 0x80000000u) ? (u ^ 0x80000000u) : ~u;
    return __uint_as_float(u);
}

// sorted-descending top-5 list of packed keys, branchless bubble insert
__device__ __forceinline__ void ins_nb(unsigned (&ks)[KTOP], unsigned k) {
    unsigned t = k;
#pragma unroll
    for (int j = 0; j < KTOP; ++j) {
        unsigned hi = t > ks[j] ? t : ks[j];
        unsigned lo = t > ks[j] ? ks[j] : t;
        ks[j] = hi; t = lo;
    }
}

// max across a 16-lane DPP row (VALU-only; keeps threshold syncs off LDS pipe)
__device__ __forceinline__ float dpp_fmax16(float x) {
    int t;
    t = __builtin_amdgcn_update_dpp(0, __float_as_int(x), 0xB1, 0xF, 0xF, true);  // xor 1
    x = fmaxf(x, __int_as_float(t));
    t = __builtin_amdgcn_update_dpp(0, __float_as_int(x), 0x4E, 0xF, 0xF, true);  // xor 2
    x = fmaxf(x, __int_as_float(t));
    t = __builtin_amdgcn_update_dpp(0, __float_as_int(x), 0x141, 0xF, 0xF, true); // xor 4
    x = fmaxf(x, __int_as_float(t));
    t = __builtin_amdgcn_update_dpp(0, __float_as_int(x), 0x140, 0xF, 0xF, true); // xor 8
    x = fmaxf(x, __int_as_float(t));
    return x;
}

// ---------- kernel 1: row L2-normalize fp32 -> fp8 e4m3 (both inputs) -------
__global__ void nrm_cast2(const float* __restrict__ memM, u8* __restrict__ mn,
                          const float* __restrict__ x, u8* __restrict__ qn) {
    int wave = threadIdx.x >> 6, lane = threadIdx.x & 63;
    int row = blockIdx.x * 4 + wave;
    const float* in;
    u8* out;
    if (row < MROWS) { in = memM + (size_t)row * CDIM; out = mn + (size_t)row * ROWB; }
    else             { int r = row - MROWS; in = x + (size_t)r * CDIM; out = qn + (size_t)r * ROWB; }
    const float* rp = in + lane * 8;
    float4 v0 = *(const float4*)rp;
    float4 v1 = *(const float4*)(rp + 4);
    float ss = v0.x * v0.x + v0.y * v0.y + v0.z * v0.z + v0.w * v0.w
             + v1.x * v1.x + v1.y * v1.y + v1.z * v1.z + v1.w * v1.w;
#pragma unroll
    for (int d = 1; d < 64; d <<= 1) ss += __shfl_xor(ss, d);
    float sc = 1.0f / fmaxf(sqrtf(ss), 1e-12f);
    int lo = __builtin_amdgcn_cvt_pk_fp8_f32(v0.x * sc, v0.y * sc, 0, false);
    lo     = __builtin_amdgcn_cvt_pk_fp8_f32(v0.z * sc, v0.w * sc, lo, true);
    int hi = __builtin_amdgcn_cvt_pk_fp8_f32(v1.x * sc, v1.y * sc, 0, false);
    hi     = __builtin_amdgcn_cvt_pk_fp8_f32(v1.z * sc, v1.w * sc, hi, true);
    uint2 o; o.x = (unsigned)lo; o.y = (unsigned)hi;
    *(uint2*)(out + lane * 8) = o;
}

// ---------- async staging: one call moves 2 rows (1 KB), XOR chunk swizzle --
// Row r: global 16B-chunk c stored at LDS slot c ^ (r&7). DMA dst is uniform
// base + lane*16; lane i covers row r0+2j+(i>>5), chunk (i&31)^(row&7) --
// the XOR stays inside the row's 512B, global access is one 1KB segment.
__device__ __forceinline__ void stage_tile(const u8* __restrict__ mn, int nb,
                                           u8* buf, int wave, int lane) {
    const int r0 = wave * 8;
    const int li = lane & 31, half = lane >> 5;
#pragma unroll
    for (int j = 0; j < 4; ++j) {
        const int row = r0 + 2 * j + half;
        const u8* src = mn + (size_t)(nb + row) * ROWB + ((li ^ (row & 7)) * 16);
        __builtin_amdgcn_global_load_lds(
            (const __attribute__((address_space(1))) void*)src,
            (__attribute__((address_space(3))) void*)(buf + (r0 + 2 * j) * ROWB),
            16, 0, 0);
    }
}

// ---------- kernel 2: fused fp8 MFMA sim + per-chunk top-5 ------------------
// grid = (NC, BS/TQ) = (8,64), block 256 (4 waves), 2 blocks/CU, 2 waves/SIMD.
// Wave holds 32 queries' A-frags (64 VGPRs). K-permutation: MFMA pair t
// assigns lane-quad q global k-range [64t+16q, 64t+16q+15]; low 8B -> instr
// 2t, high 8B -> instr 2t+1. A and B use the same permutation -> dot product
// unchanged, and every operand fetch is a single b128.
__global__ __launch_bounds__(256, 2) void simtopk(
        const u8* __restrict__ qn, const u8* __restrict__ mn,
        unsigned* __restrict__ cand) {
    __shared__ __align__(16) u8 Bt[2][TN * ROWB];   // 2 x 16 KiB

    const int tid  = threadIdx.x;
    const int wave = tid >> 6, lane = tid & 63;
    const int quad = lane >> 4, c16 = lane & 15;
    const int nc = blockIdx.x;
    const int qt = blockIdx.y;
    const int qw = qt * TQ + wave * 32;
    const int nb0 = nc * CHUNK;

    // persistent A fragments: 2 q-subtiles x 8 pair-chunks x 16B = 64 VGPRs
    long2 a[2][8];
#pragma unroll
    for (int s = 0; s < 2; ++s) {
        const u8* p = qn + (size_t)(qw + s * 16 + c16) * ROWB + quad * 16;
#pragma unroll
        for (int t = 0; t < 8; ++t)
            a[s][t] = *(const long2*)(p + t * 64);
    }

    unsigned keys[8][KTOP];
    float thr[8];
#pragma unroll
    for (int l = 0; l < 8; ++l) {
        thr[l] = -2.0f;
#pragma unroll
        for (int j = 0; j < KTOP; ++j) keys[l][j] = KEY_INIT;
    }

    const int sw = c16 & 7;                    // read-side slot XOR

    stage_tile(mn, nb0, &Bt[0][0], wave, lane);   // prefetch tile 0

    for (int it = 0; it < ITERS; ++it) {
        __syncthreads();   // drains async loads issued a full iter ago; syncs waves
        if (it + 1 < ITERS)
            stage_tile(mn, nb0 + (it + 1) * TN, &Bt[(it + 1) & 1][0], wave, lane);

        const u8* bb = &Bt[it & 1][c16 * ROWB];
        f32x4 acc00 = {0.f, 0.f, 0.f, 0.f}, acc01 = {0.f, 0.f, 0.f, 0.f};
        f32x4 acc10 = {0.f, 0.f, 0.f, 0.f}, acc11 = {0.f, 0.f, 0.f, 0.f};
#pragma unroll
        for (int t = 0; t < 8; ++t) {
            const int slot = ((t * 4 + quad) ^ sw) * 16;
            long2 b0 = *(const long2*)(bb + slot);               // row c16
            long2 b1 = *(const long2*)(bb + 16 * ROWB + slot);   // row 16+c16
            acc00 = __builtin_amdgcn_mfma_f32_16x16x32_fp8_fp8(a[0][t].x, b0.x, acc00, 0, 0, 0);
            acc00 = __builtin_amdgcn_mfma_f32_16x16x32_fp8_fp8(a[0][t].y, b0.y, acc00, 0, 0, 0);
            acc01 = __builtin_amdgcn_mfma_f32_16x16x32_fp8_fp8(a[0][t].x, b1.x, acc01, 0, 0, 0);
            acc01 = __builtin_amdgcn_mfma_f32_16x16x32_fp8_fp8(a[0][t].y, b1.y, acc01, 0, 0, 0);
            acc10 = __builtin_amdgcn_mfma_f32_16x16x32_fp8_fp8(a[1][t].x, b0.x, acc10, 0, 0, 0);
            acc10 = __builtin_amdgcn_mfma_f32_16x16x32_fp8_fp8(a[1][t].y, b0.y, acc10, 0, 0, 0);
            acc11 = __builtin_amdgcn_mfma_f32_16x16x32_fp8_fp8(a[1][t].x, b1.x, acc11, 0, 0, 0);
            acc11 = __builtin_amdgcn_mfma_f32_16x16x32_fp8_fp8(a[1][t].y, b1.y, acc11, 0, 0, 0);
        }

        const int nb = nb0 + it * TN;
        const int n0 = nb + c16, n1 = nb + 16 + c16;
        // shared-threshold filter: thr[l] <= true running 5th-best of q-row l
#pragma unroll
        for (int j = 0; j < 4; ++j) {
            if (acc00[j] > thr[j])     ins_nb(keys[j],     enc_key(acc00[j], n0));
            if (acc01[j] > thr[j])     ins_nb(keys[j],     enc_key(acc01[j], n1));
            if (acc10[j] > thr[4 + j]) ins_nb(keys[4 + j], enc_key(acc10[j], n0));
            if (acc11[j] > thr[4 + j]) ins_nb(keys[4 + j], enc_key(acc11[j], n1));
        }
        if ((it & 3) == 3) {
#pragma unroll
            for (int l = 0; l < 8; ++l)
                thr[l] = dpp_fmax16(fmaxf(thr[l], dec_score(keys[l][KTOP - 1])));
        }
    }

    // merge the 16 column-lanes of each quad (disjoint n subsets -> union top5)
#pragma unroll
    for (int d = 1; d <= 8; d <<= 1) {
#pragma unroll
        for (int l = 0; l < 8; ++l) {
            unsigned rk[KTOP];
#pragma unroll
            for (int j = 0; j < KTOP; ++j) rk[j] = (unsigned)__shfl_xor((int)keys[l][j], d);
#pragma unroll
            for (int j = 0; j < KTOP; ++j) ins_nb(keys[l], rk[j]);
        }
    }

    // writer lane c16==l emits list l for query qw + (l>>2)*16 + quad*4 + (l&3)
#pragma unroll
    for (int l = 0; l < 8; ++l) {
        if (c16 == l) {
            const int q = qw + (l >> 2) * 16 + quad * 4 + (l & 3);
            unsigned* cp = cand + ((size_t)q * NC + nc) * KTOP;
#pragma unroll
            for (int j = 0; j < KTOP; ++j) cp[j] = keys[l][j];
        }
    }
}

// ---------- kernel 3: global top-5 merge + softmax + gather + residual ------
__global__ void epilogue(const float* __restrict__ x, const float* __restrict__ mem,
                         const unsigned* __restrict__ cand, float* __restrict__ out) {
    int wave = threadIdx.x >> 6, lane = threadIdx.x & 63;
    int q = blockIdx.x * 4 + wave;

    unsigned key = (lane < NC * KTOP) ? cand[(size_t)q * (NC * KTOP) + lane] : 0u;
    float s[KTOP]; int id[KTOP];
#pragma unroll
    for (int k = 0; k < KTOP; ++k) {
        unsigned m = key;
#pragma unroll
        for (int d = 32; d; d >>= 1) {
            unsigned o = (unsigned)__shfl_xor((int)m, d);
            m = o > m ? o : m;
        }
        s[k] = dec_score(m);
        id[k] = (int)(m & 0x7FFFu);
        unsigned long long b = __ballot(key == m);
        int first = __ffsll((long long)b) - 1;
        if (lane == first) key = 0u;
    }
    float w[KTOP], sum = 0.f;
#pragma unroll
    for (int k = 0; k < KTOP; ++k) { w[k] = expf(s[k] - s[0]); sum += w[k]; }
    float inv = 0.5f / sum;

    int c = lane * 8;
    const float4* xp = (const float4*)(x + (size_t)q * CDIM + c);
    float4 o0 = xp[0], o1 = xp[1];
#pragma unroll
    for (int k = 0; k < KTOP; ++k) {
        float wk = w[k] * inv;
        const float4* mp = (const float4*)(mem + (size_t)id[k] * CDIM + c);
        float4 g0 = mp[0], g1 = mp[1];
        o0.x += wk * g0.x; o0.y += wk * g0.y; o0.z += wk * g0.z; o0.w += wk * g0.w;
        o1.x += wk * g1.x; o1.y += wk * g1.y; o1.z += wk * g1.z; o1.w += wk * g1.w;
    }
    float* op = out + (size_t)q * CDIM + c;
    *(float4*)op = o0;
    *(float4*)(op + 4) = o1;
}

// ---------- launcher --------------------------------------------------------
extern "C" void kernel_launch(void* const* d_in, const int* in_sizes, int n_in,
                              void* d_out, int out_size, void* d_ws, size_t ws_size,
                              hipStream_t stream) {
    const float* x    = (const float*)d_in[0];   // [4,2048,512] fp32
    const float* memM = (const float*)d_in[1];   // [32768,512] fp32
    float* out = (float*)d_out;                  // fp32 output

    // workspace layout: mn fp8 [M][512B] | qn fp8 [BS][512B] | cand u32 [BS][NC][5]
    u8* mn = (u8*)d_ws;
    u8* qn = mn + (size_t)MROWS * ROWB;
    unsigned* cand = (unsigned*)(qn + (size_t)BS * ROWB);

    nrm_cast2<<<(MROWS + BS) / 4, 256, 0, stream>>>(memM, mn, x, qn);
    simtopk<<<dim3(NC, BS / TQ), 256, 0, stream>>>(qn, mn, cand);
    epilogue<<<BS / 4, 256, 0, stream>>>(x, memM, cand, out);
}